// Round 1
// baseline (1577.078 us; speedup 1.0000x reference)
//
#include <hip/hip_runtime.h>
#include <math.h>

#define T_SEQ 2048
#define C_DIM 1024
#define H_DIM 64
#define N_BATCH 8
#define SCALE 0.125f

// ---------------------------------------------------------------------------
// Kernel 1: projection GEMM. out[m][n] = sum_k x[m][k] * W[n][k]
// M = B*T = 16384 (64-row tiles), K = 1024, N = 64. grid (256, 3), block 256.
// LDS tiles stored k-major so the inner loop reads float4 (ds_read_b128).
// ---------------------------------------------------------------------------
__global__ __launch_bounds__(256) void proj_kernel(
    const float* __restrict__ x, const float* __restrict__ Wq,
    const float* __restrict__ Wk, const float* __restrict__ Wv,
    float* __restrict__ qo, float* __restrict__ ko, float* __restrict__ vo)
{
    const int which = blockIdx.y;
    const float* __restrict__ W = (which == 0) ? Wq : ((which == 1) ? Wk : Wv);
    float* __restrict__ outp    = (which == 0) ? qo : ((which == 1) ? ko : vo);
    const int m0 = blockIdx.x * 64;

    __shared__ float As[16][64];   // [k][m]
    __shared__ float Bs[16][64];   // [k][n]

    const int tid = threadIdx.x;
    const int tx = tid & 15, ty = tid >> 4;
    const int lr = tid >> 2;           // 0..63 (row of A / row of W)
    const int lc = (tid & 3) * 4;      // 0,4,8,12 (k offset)

    float acc[4][4] = {};

    for (int k0 = 0; k0 < C_DIM; k0 += 16) {
        float4 a4 = *(const float4*)&x[(size_t)(m0 + lr) * C_DIM + k0 + lc];
        float4 b4 = *(const float4*)&W[(size_t)lr * C_DIM + k0 + lc];
        __syncthreads();   // prev-iter LDS reads done before overwrite
        As[lc + 0][lr] = a4.x; As[lc + 1][lr] = a4.y;
        As[lc + 2][lr] = a4.z; As[lc + 3][lr] = a4.w;
        Bs[lc + 0][lr] = b4.x; Bs[lc + 1][lr] = b4.y;
        Bs[lc + 2][lr] = b4.z; Bs[lc + 3][lr] = b4.w;
        __syncthreads();
#pragma unroll
        for (int kk = 0; kk < 16; kk++) {
            float a_[4], b_[4];
            *(float4*)a_ = *(const float4*)&As[kk][ty * 4];
            *(float4*)b_ = *(const float4*)&Bs[kk][tx * 4];
#pragma unroll
            for (int i = 0; i < 4; i++)
#pragma unroll
                for (int j = 0; j < 4; j++)
                    acc[i][j] = fmaf(a_[i], b_[j], acc[i][j]);
        }
    }
#pragma unroll
    for (int i = 0; i < 4; i++) {
        float4 o; o.x = acc[i][0]; o.y = acc[i][1]; o.z = acc[i][2]; o.w = acc[i][3];
        *(float4*)&outp[(size_t)(m0 + ty * 4 + i) * H_DIM + tx * 4] = o;
    }
}

// ---------------------------------------------------------------------------
// Kernel 2: per-key-column stats over the query axis.
// For column s: m[s] = max_{t>=s} aff[t,s], l[s] = sum_{t>=s} exp(aff - m).
// aff[t,s] = (q[t] . k[s]) * SCALE.  grid = B*32 (64 columns per block).
// ---------------------------------------------------------------------------
__global__ __launch_bounds__(256) void stats_kernel(
    const float* __restrict__ qg, const float* __restrict__ kg,
    float* __restrict__ mg, float* __restrict__ lg)
{
    const int b  = blockIdx.x >> 5;
    const int s0 = (blockIdx.x & 31) * 64;
    const float* __restrict__ qb = qg + (size_t)b * T_SEQ * H_DIM;
    const float* __restrict__ kb = kg + (size_t)b * T_SEQ * H_DIM;

    __shared__ float KsT[64][68];  // [c][s]
    __shared__ float QsT[64][68];  // [c][t]
    __shared__ float RM[16][65];
    __shared__ float RL[16][65];

    const int tid = threadIdx.x;
    const int tx = tid & 15, ty = tid >> 4;
    const int lr = tid >> 2;             // 0..63 row
    const int lcb = (tid & 3) * 16;      // 16-col chunk base

    // load K tile (transposed into [c][s]) -- fixed for the whole block
#pragma unroll
    for (int u = 0; u < 4; u++) {
        const int c0 = lcb + u * 4;
        float4 t4 = *(const float4*)&kb[(size_t)(s0 + lr) * H_DIM + c0];
        KsT[c0 + 0][lr] = t4.x; KsT[c0 + 1][lr] = t4.y;
        KsT[c0 + 2][lr] = t4.z; KsT[c0 + 3][lr] = t4.w;
    }

    float mloc[4], lloc[4];
#pragma unroll
    for (int j = 0; j < 4; j++) { mloc[j] = -INFINITY; lloc[j] = 0.0f; }

    for (int t0 = s0; t0 < T_SEQ; t0 += 64) {
        __syncthreads();   // prev-iter QsT reads done
#pragma unroll
        for (int u = 0; u < 4; u++) {
            const int c0 = lcb + u * 4;
            float4 t4 = *(const float4*)&qb[(size_t)(t0 + lr) * H_DIM + c0];
            QsT[c0 + 0][lr] = t4.x; QsT[c0 + 1][lr] = t4.y;
            QsT[c0 + 2][lr] = t4.z; QsT[c0 + 3][lr] = t4.w;
        }
        __syncthreads();

        float acc[4][4] = {};
#pragma unroll
        for (int c = 0; c < 64; c++) {
            float a_[4], b_[4];
            *(float4*)a_ = *(const float4*)&QsT[c][ty * 4];
            *(float4*)b_ = *(const float4*)&KsT[c][tx * 4];
#pragma unroll
            for (int i = 0; i < 4; i++)
#pragma unroll
                for (int j = 0; j < 4; j++)
                    acc[i][j] = fmaf(a_[i], b_[j], acc[i][j]);
        }
        // online (m,l) update; mask t < s (softmax over t >= s only)
#pragma unroll
        for (int j = 0; j < 4; j++) {
            const int s = s0 + tx * 4 + j;
#pragma unroll
            for (int i = 0; i < 4; i++) {
                const int t = t0 + ty * 4 + i;
                if (t >= s) {
                    const float a = acc[i][j] * SCALE;
                    if (a > mloc[j]) {
                        lloc[j] = lloc[j] * __expf(mloc[j] - a) + 1.0f;
                        mloc[j] = a;
                    } else {
                        lloc[j] += __expf(a - mloc[j]);
                    }
                }
            }
        }
    }

    // reduce the 16 thread-rows per column
#pragma unroll
    for (int j = 0; j < 4; j++) { RM[ty][tx * 4 + j] = mloc[j]; RL[ty][tx * 4 + j] = lloc[j]; }
    __syncthreads();
    if (tid < 64) {
        float M = -INFINITY, L = 0.0f;
#pragma unroll
        for (int r = 0; r < 16; r++) {
            const float mm = RM[r][tid], ll = RL[r][tid];
            if (mm > -INFINITY) {           // skip empty partials (avoid inf-inf NaN)
                if (mm > M) { L = L * __expf(M - mm) + ll; M = mm; }
                else        { L += ll * __expf(mm - M); }
            }
        }
        mg[b * T_SEQ + s0 + tid] = M;
        lg[b * T_SEQ + s0 + tid] = L;
    }
}

// ---------------------------------------------------------------------------
// Kernel 3: out[t] = sum_{s<=t} exp(aff[t,s]-m[s])/l[s] * v[s].
// Flash-style: 64 query rows per block, stream s-tiles 0..t0.
// ---------------------------------------------------------------------------
__global__ __launch_bounds__(256) void out_kernel(
    const float* __restrict__ qg, const float* __restrict__ kg,
    const float* __restrict__ vg, const float* __restrict__ mg,
    const float* __restrict__ lg, float* __restrict__ outg)
{
    const int b  = blockIdx.x >> 5;
    const int t0 = (blockIdx.x & 31) * 64;
    const float* __restrict__ qb = qg + (size_t)b * T_SEQ * H_DIM;
    const float* __restrict__ kb = kg + (size_t)b * T_SEQ * H_DIM;
    const float* __restrict__ vb = vg + (size_t)b * T_SEQ * H_DIM;

    __shared__ float QsT[64][68];  // [c][t]
    __shared__ float KsT[64][68];  // [c][s]
    __shared__ float Ps[64][68];   // [s][t]
    __shared__ float Vs[64][68];   // [s][h]
    __shared__ float Ms[64];
    __shared__ float Li[64];       // 1/l

    const int tid = threadIdx.x;
    const int tx = tid & 15, ty = tid >> 4;
    const int lr = tid >> 2;
    const int lcb = (tid & 3) * 16;

    // load Q tile once (transposed)
#pragma unroll
    for (int u = 0; u < 4; u++) {
        const int c0 = lcb + u * 4;
        float4 t4 = *(const float4*)&qb[(size_t)(t0 + lr) * H_DIM + c0];
        QsT[c0 + 0][lr] = t4.x; QsT[c0 + 1][lr] = t4.y;
        QsT[c0 + 2][lr] = t4.z; QsT[c0 + 3][lr] = t4.w;
    }

    float oacc[4][4] = {};

    for (int s0 = 0; s0 <= t0; s0 += 64) {
        __syncthreads();   // prev-iter KsT/Vs/Ps reads done
#pragma unroll
        for (int u = 0; u < 4; u++) {
            const int c0 = lcb + u * 4;
            float4 t4 = *(const float4*)&kb[(size_t)(s0 + lr) * H_DIM + c0];
            KsT[c0 + 0][lr] = t4.x; KsT[c0 + 1][lr] = t4.y;
            KsT[c0 + 2][lr] = t4.z; KsT[c0 + 3][lr] = t4.w;
            float4 v4 = *(const float4*)&vb[(size_t)(s0 + lr) * H_DIM + c0];
            *(float4*)&Vs[lr][c0] = v4;
        }
        if (tid < 64) {
            Ms[tid] = mg[b * T_SEQ + s0 + tid];
            Li[tid] = 1.0f / lg[b * T_SEQ + s0 + tid];
        }
        __syncthreads();

        // aff tile
        float acc[4][4] = {};
#pragma unroll
        for (int c = 0; c < 64; c++) {
            float a_[4], b_[4];
            *(float4*)a_ = *(const float4*)&QsT[c][ty * 4];
            *(float4*)b_ = *(const float4*)&KsT[c][tx * 4];
#pragma unroll
            for (int i = 0; i < 4; i++)
#pragma unroll
                for (int j = 0; j < 4; j++)
                    acc[i][j] = fmaf(a_[i], b_[j], acc[i][j]);
        }
        // P = exp(aff - m)/l, masked; write transposed [s][t] as float4
#pragma unroll
        for (int j = 0; j < 4; j++) {
            const int s = s0 + tx * 4 + j;
            const float mm = Ms[tx * 4 + j];
            const float li = Li[tx * 4 + j];
            float p_[4];
#pragma unroll
            for (int i = 0; i < 4; i++) {
                const int t = t0 + ty * 4 + i;
                p_[i] = (s <= t) ? __expf(acc[i][j] * SCALE - mm) * li : 0.0f;
            }
            *(float4*)&Ps[tx * 4 + j][ty * 4] = *(float4*)p_;
        }
        __syncthreads();

        // PV: oacc[t][h] += P[t][s] * V[s][h]
#pragma unroll
        for (int s = 0; s < 64; s++) {
            float p_[4], v_[4];
            *(float4*)p_ = *(const float4*)&Ps[s][ty * 4];
            *(float4*)v_ = *(const float4*)&Vs[s][tx * 4];
#pragma unroll
            for (int i = 0; i < 4; i++)
#pragma unroll
                for (int j = 0; j < 4; j++)
                    oacc[i][j] = fmaf(p_[i], v_[j], oacc[i][j]);
        }
    }

#pragma unroll
    for (int i = 0; i < 4; i++) {
        float4 o; o.x = oacc[i][0]; o.y = oacc[i][1]; o.z = oacc[i][2]; o.w = oacc[i][3];
        *(float4*)&outg[(size_t)(b * T_SEQ + t0 + ty * 4 + i) * H_DIM + tx * 4] = o;
    }
}

// ---------------------------------------------------------------------------
extern "C" void kernel_launch(void* const* d_in, const int* in_sizes, int n_in,
                              void* d_out, int out_size, void* d_ws, size_t ws_size,
                              hipStream_t stream) {
    const float* x  = (const float*)d_in[0];
    const float* Wq = (const float*)d_in[1];
    const float* Wk = (const float*)d_in[2];
    const float* Wv = (const float*)d_in[3];
    float* out = (float*)d_out;

    float* w = (float*)d_ws;
    const size_t NTOK = (size_t)N_BATCH * T_SEQ;        // 16384
    float* q = w;
    float* k = w + NTOK * H_DIM;                        // +1,048,576
    float* v = w + 2 * NTOK * H_DIM;
    float* m = w + 3 * NTOK * H_DIM;
    float* l = m + NTOK;

    proj_kernel<<<dim3(256, 3), 256, 0, stream>>>(x, Wq, Wk, Wv, q, k, v);
    stats_kernel<<<256, 256, 0, stream>>>(q, k, m, l);
    out_kernel<<<256, 256, 0, stream>>>(q, k, v, m, l, out);
}